// Round 16
// baseline (55.500 us; speedup 1.0000x reference)
//
#include <hip/hip_runtime.h>

// (min,+) DP, wave-specialized. 2 images/block, SIX waves, grid=256 (1/CU):
//   wave 0,1: chain img A,B          (the serial recurrence, latency-bound)
//   wave 2,3: prep1 img A,B  rows 0-17 of each chunk  (own SIMD, 18 rows)
//   wave 4,5: prep2 img A,B  rows 18-31               (shares SIMD w/ chain)
// Theory: chain ran 295cyc/row with 5 waves/block (R9) vs 400 with 8 (R14/15)
// -> SIMD issue contention. 6 waves thins co-tenancy; prep issue cost
// (~150-250cyc/row) means 2 preps/image still cover the chain.
// Cooperative chunk 0: all 6 waves prep it (chains do rows 0-10), cutting
// startup. min3-tree shortens the loop-carried path by one level.
// LDS 128KB double buffer; 1 block/CU is grid-enforced (256 blocks).

#define HH 256
#define WW 256
#define CH 32          // rows per chunk
#define NCH 8          // chunks per image
#define NULLV 1e30f

template<int CTRL, int ROWM>
__device__ __forceinline__ float dpp_mov(float x, float oldv) {
    return __builtin_bit_cast(float, __builtin_amdgcn_update_dpp(
        __builtin_bit_cast(int, oldv), __builtin_bit_cast(int, x),
        CTRL, ROWM, 0xF, false));
}

__device__ __forceinline__ float wave_iscan_add(float x) {
    x += dpp_mov<0x111, 0xF>(x, 0.0f);  // row_shr:1
    x += dpp_mov<0x112, 0xF>(x, 0.0f);  // row_shr:2
    x += dpp_mov<0x114, 0xF>(x, 0.0f);  // row_shr:4
    x += dpp_mov<0x118, 0xF>(x, 0.0f);  // row_shr:8
    x += dpp_mov<0x142, 0xA>(x, 0.0f);  // row_bcast:15 -> rows 1,3
    x += dpp_mov<0x143, 0xC>(x, 0.0f);  // row_bcast:31 -> rows 2,3
    return x;
}

__device__ __forceinline__ float wave_iscan_min(float x) {
    x = fminf(x, dpp_mov<0x111, 0xF>(x, NULLV));
    x = fminf(x, dpp_mov<0x112, 0xF>(x, NULLV));
    x = fminf(x, dpp_mov<0x114, 0xF>(x, NULLV));
    x = fminf(x, dpp_mov<0x118, 0xF>(x, NULLV));
    x = fminf(x, dpp_mov<0x142, 0xA>(x, NULLV));
    x = fminf(x, dpp_mov<0x143, 0xC>(x, NULLV));
    return x;
}

__device__ __forceinline__ float softplus_f(float x) {
    float ax = fabsf(x);
    float t  = __expf(-ax);
    return fmaxf(x, 0.0f) + __logf(1.0f + t);
}

// full-row cumsum of softplus for one row; returns S at cols 4l..4l+3
__device__ __forceinline__ float4 prep_row(float4 c) {
    float t0 = softplus_f(c.x);
    float t1 = t0 + softplus_f(c.y);
    float t2 = t1 + softplus_f(c.z);
    float t3 = t2 + softplus_f(c.w);
    float s    = wave_iscan_add(t3);
    float soff = dpp_mov<0x138, 0xF>(s, 0.0f);  // wave_shr:1, lane0 -> 0
    return make_float4(soff + t0, soff + t1, soff + t2, soff + t3);
}

template<int NR>
__device__ __forceinline__ void load_rows(const float4* gp, int r0, float4* L) {
#pragma unroll
    for (int i = 0; i < NR; ++i) L[i] = gp[(size_t)(r0 + i) * 64];
}

// prep NR rows from L into dst (= &buf[row0][0])
template<int NR>
__device__ __forceinline__ void prep_store(const float4* L, float* dst, int lane) {
#pragma unroll
    for (int i = 0; i < NR; ++i)
        *reinterpret_cast<float4*>(&dst[i * WW + lane * 4]) = prep_row(L[i]);
}

__global__ __launch_bounds__(384, 1) void dp_kernel(const float* __restrict__ img,
                                                    float* __restrict__ out) {
    const int tid = threadIdx.x;
    const int wid = tid >> 6;
    const int lane = tid & 63;

    // [image][buffer][row][col] -> 128 KB
    __shared__ __align__(16) float sbuf[2][2][CH][WW];

    const int imgi = wid & 1;
    const float* gbase = img + (size_t)(2 * blockIdx.x + imgi) * HH * WW;
    const float4* gp = reinterpret_cast<const float4*>(gbase) + lane;

    if (wid < 2) {
        // ---------------- chain waves (one per image) ----------------
        // cooperative chunk-0: chain preps rows 0..10
        {
            float4 C[11];
            load_rows<11>(gp, 0, C);
            prep_store<11>(C, &sbuf[imgi][0][0][0], lane);
        }
        __syncthreads();                       // B0: chunk 0 ready
        __builtin_amdgcn_s_setprio(1);

        float v0, v1, v2, v3;
        auto row_step = [&](const float4& S) {
            float soff = dpp_mov<0x138, 0xF>(S.w, 0.0f);  // S[4l-1]
            float vm1  = dpp_mov<0x138, 0xF>(v3, NULLV);  // v[4l-1]
            float B0 = fminf(v0, vm1) - soff;
            float B1 = fminf(v1, v0) - S.x;
            float B2 = fminf(v2, v1) - S.y;
            float B3 = fminf(v3, v2) - S.z;
            float m1 = fminf(B0, B1);
            float p  = fminf(B2, B3);          // parallel pair
            float m2 = fminf(m1, B2);
            float m3 = fminf(m1, p);           // depth 2, not 3
            float mm   = wave_iscan_min(m3);
            float moff = dpp_mov<0x138, 0xF>(mm, NULLV);
            v0 = S.x + fminf(moff, B0);
            v1 = S.y + fminf(moff, m1);
            v2 = S.z + fminf(moff, m2);
            v3 = S.w + fminf(moff, m3);
        };

#define RD8(P, buf, r0)                                                  \
    P##0 = *reinterpret_cast<const float4*>(&(buf)[(r0) + 0][lane * 4]); \
    P##1 = *reinterpret_cast<const float4*>(&(buf)[(r0) + 1][lane * 4]); \
    P##2 = *reinterpret_cast<const float4*>(&(buf)[(r0) + 2][lane * 4]); \
    P##3 = *reinterpret_cast<const float4*>(&(buf)[(r0) + 3][lane * 4]); \
    P##4 = *reinterpret_cast<const float4*>(&(buf)[(r0) + 4][lane * 4]); \
    P##5 = *reinterpret_cast<const float4*>(&(buf)[(r0) + 5][lane * 4]); \
    P##6 = *reinterpret_cast<const float4*>(&(buf)[(r0) + 6][lane * 4]); \
    P##7 = *reinterpret_cast<const float4*>(&(buf)[(r0) + 7][lane * 4]);
#define ST8(P)                                                           \
    row_step(P##0); row_step(P##1); row_step(P##2); row_step(P##3);      \
    row_step(P##4); row_step(P##5); row_step(P##6); row_step(P##7);

        float4 A0, A1, A2, A3, A4, A5, A6, A7;
        float4 B0, B1, B2, B3, B4, B5, B6, B7;

        // chunk 0 (peel row-0 init)
        {
            const float(*buf)[WW] = sbuf[imgi][0];
            RD8(A, buf, 0); RD8(B, buf, 8);
            v0 = A0.x; v1 = A0.y; v2 = A0.z; v3 = A0.w;
            row_step(A1); row_step(A2); row_step(A3);
            row_step(A4); row_step(A5); row_step(A6); row_step(A7);
            RD8(A, buf, 16);
            ST8(B);
            RD8(B, buf, 24);
            ST8(A);
            ST8(B);
        }
        // chunks 1..7
        for (int k = 1; k < NCH; ++k) {
            __syncthreads();                   // Bk: chunk k ready
            const float(*buf)[WW] = sbuf[imgi][k & 1];
            RD8(A, buf, 0); RD8(B, buf, 8);
            ST8(A);
            RD8(A, buf, 16);
            ST8(B);
            RD8(B, buf, 24);
            ST8(A);
            ST8(B);
        }
#undef RD8
#undef ST8
        if (lane == 63) out[2 * blockIdx.x + imgi] = v3;
    } else if (wid < 4) {
        // ------------- prep1 (free SIMD): chunk0 rows 11-21; steady 0-17 -------------
        {
            float4 C[11];
            load_rows<11>(gp, 11, C);
            prep_store<11>(C, &sbuf[imgi][0][11][0], lane);
        }
        float4 L[18];
        load_rows<18>(gp, CH + 0, L);          // chunk 1 rows 0-17
        __syncthreads();                       // B0
        for (int k = 1; k < NCH; ++k) {
            float4 N[18];
            if (k + 1 < NCH) load_rows<18>(gp, (k + 1) * CH + 0, N);
            prep_store<18>(L, &sbuf[imgi][k & 1][0][0], lane);
            __syncthreads();                   // Bk
            if (k + 1 < NCH) {
#pragma unroll
                for (int i = 0; i < 18; ++i) L[i] = N[i];
            }
        }
    } else {
        // ------------- prep2 (shares SIMD w/ chain): chunk0 rows 22-31; steady 18-31 -------------
        {
            float4 C[10];
            load_rows<10>(gp, 22, C);
            prep_store<10>(C, &sbuf[imgi][0][22][0], lane);
        }
        float4 L[14];
        load_rows<14>(gp, CH + 18, L);         // chunk 1 rows 18-31
        __syncthreads();                       // B0
        for (int k = 1; k < NCH; ++k) {
            float4 N[14];
            if (k + 1 < NCH) load_rows<14>(gp, (k + 1) * CH + 18, N);
            prep_store<14>(L, &sbuf[imgi][k & 1][18][0], lane);
            __syncthreads();                   // Bk
            if (k + 1 < NCH) {
#pragma unroll
                for (int i = 0; i < 14; ++i) L[i] = N[i];
            }
        }
    }
}

extern "C" void kernel_launch(void* const* d_in, const int* in_sizes, int n_in,
                              void* d_out, int out_size, void* d_ws, size_t ws_size,
                              hipStream_t stream) {
    const float* img = (const float*)d_in[0];
    float* out = (float*)d_out;
    dp_kernel<<<out_size / 2, 384, 0, stream>>>(img, out);
}

// Round 17
// 46.184 us; speedup vs baseline: 1.2017x; 1.2017x over previous
//
#include <hip/hip_runtime.h>

// (min,+) DP, wave-specialized. 2 images/block, 8 waves, grid=256 (1/CU):
//   wave 0,1: chain img A,B (serial recurrence)
//   waves 2-7: prep, 3 per image (steady rows 0-5 / 6-10 / 11-15 per chunk)
// CH=16: 16 barriers/image (R14 had 32), LDS 64KB double-buffered, and prep
// register arrays (L[6]+N[6]=48 VGPR) stay spill-free (R15/16's CH=32 preps
// spilled -> 392KB scratch writes -> prep-bound regression).
// Cooperative chunk 0: all 8 waves prep 4 rows each. min3-tree row_step.

#define HH 256
#define WW 256
#define CH 16          // rows per chunk
#define NCH 16         // chunks per image
#define NULLV 1e30f

template<int CTRL, int ROWM>
__device__ __forceinline__ float dpp_mov(float x, float oldv) {
    return __builtin_bit_cast(float, __builtin_amdgcn_update_dpp(
        __builtin_bit_cast(int, oldv), __builtin_bit_cast(int, x),
        CTRL, ROWM, 0xF, false));
}

__device__ __forceinline__ float wave_iscan_add(float x) {
    x += dpp_mov<0x111, 0xF>(x, 0.0f);  // row_shr:1
    x += dpp_mov<0x112, 0xF>(x, 0.0f);  // row_shr:2
    x += dpp_mov<0x114, 0xF>(x, 0.0f);  // row_shr:4
    x += dpp_mov<0x118, 0xF>(x, 0.0f);  // row_shr:8
    x += dpp_mov<0x142, 0xA>(x, 0.0f);  // row_bcast:15 -> rows 1,3
    x += dpp_mov<0x143, 0xC>(x, 0.0f);  // row_bcast:31 -> rows 2,3
    return x;
}

__device__ __forceinline__ float wave_iscan_min(float x) {
    x = fminf(x, dpp_mov<0x111, 0xF>(x, NULLV));
    x = fminf(x, dpp_mov<0x112, 0xF>(x, NULLV));
    x = fminf(x, dpp_mov<0x114, 0xF>(x, NULLV));
    x = fminf(x, dpp_mov<0x118, 0xF>(x, NULLV));
    x = fminf(x, dpp_mov<0x142, 0xA>(x, NULLV));
    x = fminf(x, dpp_mov<0x143, 0xC>(x, NULLV));
    return x;
}

__device__ __forceinline__ float softplus_f(float x) {
    float ax = fabsf(x);
    float t  = __expf(-ax);
    return fmaxf(x, 0.0f) + __logf(1.0f + t);
}

// full-row cumsum of softplus for one row; returns S at cols 4l..4l+3
__device__ __forceinline__ float4 prep_row(float4 c) {
    float t0 = softplus_f(c.x);
    float t1 = t0 + softplus_f(c.y);
    float t2 = t1 + softplus_f(c.z);
    float t3 = t2 + softplus_f(c.w);
    float s    = wave_iscan_add(t3);
    float soff = dpp_mov<0x138, 0xF>(s, 0.0f);  // wave_shr:1, lane0 -> 0
    return make_float4(soff + t0, soff + t1, soff + t2, soff + t3);
}

template<int NR>
__device__ __forceinline__ void load_rows(const float4* gp, int r0, float4* L) {
#pragma unroll
    for (int i = 0; i < NR; ++i) L[i] = gp[(size_t)(r0 + i) * 64];
}

template<int NR>
__device__ __forceinline__ void prep_store(const float4* L, float* dst, int lane) {
#pragma unroll
    for (int i = 0; i < NR; ++i)
        *reinterpret_cast<float4*>(&dst[i * WW + lane * 4]) = prep_row(L[i]);
}

// steady-state prep worker: NR rows at chunk-offset row0, chunks 1..NCH-1,
// next chunk's loads issued before current chunk's trans-heavy compute.
template<int NR>
__device__ __forceinline__ void prep_run(const float4* gp, int row0,
                                         float* base0, float* base1, int lane) {
    float4 L[NR];
    load_rows<NR>(gp, CH + row0, L);           // chunk 1
    __syncthreads();                           // B0 (chunk 0 published by all)
    for (int k = 1; k < NCH; ++k) {
        float4 N[NR];
        if (k + 1 < NCH) load_rows<NR>(gp, (k + 1) * CH + row0, N);
        prep_store<NR>(L, (k & 1) ? base1 : base0, lane);
        __syncthreads();                       // Bk: chunk k ready
        if (k + 1 < NCH) {
#pragma unroll
            for (int i = 0; i < NR; ++i) L[i] = N[i];
        }
    }
}

__global__ __launch_bounds__(512, 1) void dp_kernel(const float* __restrict__ img,
                                                    float* __restrict__ out) {
    const int tid = threadIdx.x;
    const int wid = tid >> 6;
    const int lane = tid & 63;

    // [image][buffer][row][col] -> 64 KB
    __shared__ __align__(16) float sbuf[2][2][CH][WW];

    const int imgi = (wid < 2) ? wid : ((wid - 2) & 1);
    const float* gbase = img + (size_t)(2 * blockIdx.x + imgi) * HH * WW;
    const float4* gp = reinterpret_cast<const float4*>(gbase) + lane;

    if (wid < 2) {
        // ---------------- chain waves (one per image) ----------------
        {   // cooperative chunk-0: chain preps rows 0-3
            float4 C[4];
            load_rows<4>(gp, 0, C);
            prep_store<4>(C, &sbuf[imgi][0][0][0], lane);
        }
        __syncthreads();                       // B0: chunk 0 ready
        __builtin_amdgcn_s_setprio(1);

        float v0, v1, v2, v3;
        auto row_step = [&](const float4& S) {
            float soff = dpp_mov<0x138, 0xF>(S.w, 0.0f);  // S[4l-1]
            float vm1  = dpp_mov<0x138, 0xF>(v3, NULLV);  // v[4l-1]
            float B0 = fminf(v0, vm1) - soff;
            float B1 = fminf(v1, v0) - S.x;
            float B2 = fminf(v2, v1) - S.y;
            float B3 = fminf(v3, v2) - S.z;
            float m1 = fminf(B0, B1);
            float p  = fminf(B2, B3);
            float m2 = fminf(m1, B2);
            float m3 = fminf(m1, p);           // depth-2 tree
            float mm   = wave_iscan_min(m3);
            float moff = dpp_mov<0x138, 0xF>(mm, NULLV);
            v0 = S.x + fminf(moff, B0);
            v1 = S.y + fminf(moff, m1);
            v2 = S.z + fminf(moff, m2);
            v3 = S.w + fminf(moff, m3);
        };

#define RD8(P, buf, r0)                                                  \
    P##0 = *reinterpret_cast<const float4*>(&(buf)[(r0) + 0][lane * 4]); \
    P##1 = *reinterpret_cast<const float4*>(&(buf)[(r0) + 1][lane * 4]); \
    P##2 = *reinterpret_cast<const float4*>(&(buf)[(r0) + 2][lane * 4]); \
    P##3 = *reinterpret_cast<const float4*>(&(buf)[(r0) + 3][lane * 4]); \
    P##4 = *reinterpret_cast<const float4*>(&(buf)[(r0) + 4][lane * 4]); \
    P##5 = *reinterpret_cast<const float4*>(&(buf)[(r0) + 5][lane * 4]); \
    P##6 = *reinterpret_cast<const float4*>(&(buf)[(r0) + 6][lane * 4]); \
    P##7 = *reinterpret_cast<const float4*>(&(buf)[(r0) + 7][lane * 4]);
#define ST8(P)                                                           \
    row_step(P##0); row_step(P##1); row_step(P##2); row_step(P##3);      \
    row_step(P##4); row_step(P##5); row_step(P##6); row_step(P##7);

        float4 A0, A1, A2, A3, A4, A5, A6, A7;
        float4 B0, B1, B2, B3, B4, B5, B6, B7;

        // chunk 0 (rows 0..15; peel row-0 init)
        {
            const float(*buf)[WW] = sbuf[imgi][0];
            RD8(A, buf, 0); RD8(B, buf, 8);
            v0 = A0.x; v1 = A0.y; v2 = A0.z; v3 = A0.w;
            row_step(A1); row_step(A2); row_step(A3);
            row_step(A4); row_step(A5); row_step(A6); row_step(A7);
            ST8(B);
        }
        // chunks 1..15
        for (int k = 1; k < NCH; ++k) {
            __syncthreads();                   // Bk
            const float(*buf)[WW] = sbuf[imgi][k & 1];
            RD8(A, buf, 0); RD8(B, buf, 8);
            ST8(A);
            ST8(B);
        }
#undef RD8
#undef ST8
        if (lane == 63) out[2 * blockIdx.x + imgi] = v3;
    } else {
        // ---------------- prep waves: 3 per image ----------------
        const int pw = (wid - 2) >> 1;         // 0,1,2
        {   // cooperative chunk-0: rows 4+4pw .. 7+4pw
            float4 C[4];
            load_rows<4>(gp, 4 + 4 * pw, C);
            prep_store<4>(C, &sbuf[imgi][0][4 + 4 * pw][0], lane);
        }
        const int row0 = (pw == 0) ? 0 : (pw == 1) ? 6 : 11;  // 6/5/5 rows
        float* b0 = &sbuf[imgi][0][row0][0];
        float* b1 = &sbuf[imgi][1][row0][0];
        if (pw == 0) prep_run<6>(gp, row0, b0, b1, lane);
        else         prep_run<5>(gp, row0, b0, b1, lane);
    }
}

extern "C" void kernel_launch(void* const* d_in, const int* in_sizes, int n_in,
                              void* d_out, int out_size, void* d_ws, size_t ws_size,
                              hipStream_t stream) {
    const float* img = (const float*)d_in[0];
    float* out = (float*)d_out;
    dp_kernel<<<out_size / 2, 512, 0, stream>>>(img, out);
}

// Round 18
// 39.942 us; speedup vs baseline: 1.3895x; 1.1563x over previous
//
#include <hip/hip_runtime.h>

// (min,+) DP, wave-specialized (R17 structure, proven 46.2us, chain-bound):
//   wave 0,1: chain img A,B; waves 2-7: prep (3/image), CH=16, LDS 64KB,
//   grid=256 (1 blk/CU), coop chunk-0.
// NEW: fused in-place DPP scans. v_min_f32_dpp v,v,v row_shr:N (no
// bound_ctrl -> invalid-source lanes SKIP THE WRITE = keep own value =
// scan identity) turns each scan step into ONE instruction; s_nop 1 covers
// the 2-wait VALU->DPP hazard. Cuts the chain's loop-carried path by
// ~120cyc/row (the 6-step min-scan was ~60% of it). Prep's add-scan gets
// the same treatment with bound_ctrl:0 (reads 0 = add identity).

#define HH 256
#define WW 256
#define CH 16          // rows per chunk
#define NCH 16         // chunks per image
#define NULLV 1e30f

template<int CTRL, int ROWM>
__device__ __forceinline__ float dpp_mov(float x, float oldv) {
    return __builtin_bit_cast(float, __builtin_amdgcn_update_dpp(
        __builtin_bit_cast(int, oldv), __builtin_bit_cast(int, x),
        CTRL, ROWM, 0xF, false));
}

// 64-lane inclusive min-scan: 6 fused in-place DPP steps.
// Write-suppression (no bound_ctrl) = identity for invalid-source lanes.
__device__ __forceinline__ float wave_iscan_min(float x) {
    asm volatile(
        "s_nop 1\n\t"
        "v_min_f32_dpp %0, %0, %0 row_shr:1  row_mask:0xf bank_mask:0xf\n\t"
        "s_nop 1\n\t"
        "v_min_f32_dpp %0, %0, %0 row_shr:2  row_mask:0xf bank_mask:0xf\n\t"
        "s_nop 1\n\t"
        "v_min_f32_dpp %0, %0, %0 row_shr:4  row_mask:0xf bank_mask:0xf\n\t"
        "s_nop 1\n\t"
        "v_min_f32_dpp %0, %0, %0 row_shr:8  row_mask:0xf bank_mask:0xf\n\t"
        "s_nop 1\n\t"
        "v_min_f32_dpp %0, %0, %0 row_bcast:15 row_mask:0xa bank_mask:0xf\n\t"
        "s_nop 1\n\t"
        "v_min_f32_dpp %0, %0, %0 row_bcast:31 row_mask:0xc bank_mask:0xf"
        : "+v"(x));
    return x;
}

// 64-lane inclusive add-scan: fused in-place, bound_ctrl:0 (reads 0 = id).
__device__ __forceinline__ float wave_iscan_add(float x) {
    asm volatile(
        "s_nop 1\n\t"
        "v_add_f32_dpp %0, %0, %0 row_shr:1  row_mask:0xf bank_mask:0xf bound_ctrl:0\n\t"
        "s_nop 1\n\t"
        "v_add_f32_dpp %0, %0, %0 row_shr:2  row_mask:0xf bank_mask:0xf bound_ctrl:0\n\t"
        "s_nop 1\n\t"
        "v_add_f32_dpp %0, %0, %0 row_shr:4  row_mask:0xf bank_mask:0xf bound_ctrl:0\n\t"
        "s_nop 1\n\t"
        "v_add_f32_dpp %0, %0, %0 row_shr:8  row_mask:0xf bank_mask:0xf bound_ctrl:0\n\t"
        "s_nop 1\n\t"
        "v_add_f32_dpp %0, %0, %0 row_bcast:15 row_mask:0xa bank_mask:0xf bound_ctrl:0\n\t"
        "s_nop 1\n\t"
        "v_add_f32_dpp %0, %0, %0 row_bcast:31 row_mask:0xc bank_mask:0xf bound_ctrl:0"
        : "+v"(x));
    return x;
}

__device__ __forceinline__ float softplus_f(float x) {
    float ax = fabsf(x);
    float t  = __expf(-ax);
    return fmaxf(x, 0.0f) + __logf(1.0f + t);
}

// full-row cumsum of softplus for one row; returns S at cols 4l..4l+3
__device__ __forceinline__ float4 prep_row(float4 c) {
    float t0 = softplus_f(c.x);
    float t1 = t0 + softplus_f(c.y);
    float t2 = t1 + softplus_f(c.z);
    float t3 = t2 + softplus_f(c.w);
    float s    = wave_iscan_add(t3);
    float soff = dpp_mov<0x138, 0xF>(s, 0.0f);  // wave_shr:1, lane0 -> 0
    return make_float4(soff + t0, soff + t1, soff + t2, soff + t3);
}

template<int NR>
__device__ __forceinline__ void load_rows(const float4* gp, int r0, float4* L) {
#pragma unroll
    for (int i = 0; i < NR; ++i) L[i] = gp[(size_t)(r0 + i) * 64];
}

template<int NR>
__device__ __forceinline__ void prep_store(const float4* L, float* dst, int lane) {
#pragma unroll
    for (int i = 0; i < NR; ++i)
        *reinterpret_cast<float4*>(&dst[i * WW + lane * 4]) = prep_row(L[i]);
}

// steady-state prep worker: NR rows at chunk-offset row0, chunks 1..NCH-1,
// next chunk's loads issued before current chunk's trans-heavy compute.
template<int NR>
__device__ __forceinline__ void prep_run(const float4* gp, int row0,
                                         float* base0, float* base1, int lane) {
    float4 L[NR];
    load_rows<NR>(gp, CH + row0, L);           // chunk 1
    __syncthreads();                           // B0 (chunk 0 published by all)
    for (int k = 1; k < NCH; ++k) {
        float4 N[NR];
        if (k + 1 < NCH) load_rows<NR>(gp, (k + 1) * CH + row0, N);
        prep_store<NR>(L, (k & 1) ? base1 : base0, lane);
        __syncthreads();                       // Bk: chunk k ready
        if (k + 1 < NCH) {
#pragma unroll
            for (int i = 0; i < NR; ++i) L[i] = N[i];
        }
    }
}

__global__ __launch_bounds__(512, 1) void dp_kernel(const float* __restrict__ img,
                                                    float* __restrict__ out) {
    const int tid = threadIdx.x;
    const int wid = tid >> 6;
    const int lane = tid & 63;

    // [image][buffer][row][col] -> 64 KB
    __shared__ __align__(16) float sbuf[2][2][CH][WW];

    const int imgi = (wid < 2) ? wid : ((wid - 2) & 1);
    const float* gbase = img + (size_t)(2 * blockIdx.x + imgi) * HH * WW;
    const float4* gp = reinterpret_cast<const float4*>(gbase) + lane;

    if (wid < 2) {
        // ---------------- chain waves (one per image) ----------------
        {   // cooperative chunk-0: chain preps rows 0-3
            float4 C[4];
            load_rows<4>(gp, 0, C);
            prep_store<4>(C, &sbuf[imgi][0][0][0], lane);
        }
        __syncthreads();                       // B0: chunk 0 ready
        __builtin_amdgcn_s_setprio(1);

        float v0, v1, v2, v3;
        auto row_step = [&](const float4& S) {
            float soff = dpp_mov<0x138, 0xF>(S.w, 0.0f);  // S[4l-1]
            float vm1  = dpp_mov<0x138, 0xF>(v3, NULLV);  // v[4l-1]
            float B0 = fminf(v0, vm1) - soff;
            float B1 = fminf(v1, v0) - S.x;
            float B2 = fminf(v2, v1) - S.y;
            float B3 = fminf(v3, v2) - S.z;
            float m1 = fminf(B0, B1);
            float p  = fminf(B2, B3);
            float m2 = fminf(m1, B2);
            float m3 = fminf(m1, p);           // depth-2 tree
            float mm   = wave_iscan_min(m3);   // fused DPP scan (asm)
            float moff = dpp_mov<0x138, 0xF>(mm, NULLV);
            v0 = S.x + fminf(moff, B0);
            v1 = S.y + fminf(moff, m1);
            v2 = S.z + fminf(moff, m2);
            v3 = S.w + fminf(moff, m3);
        };

#define RD8(P, buf, r0)                                                  \
    P##0 = *reinterpret_cast<const float4*>(&(buf)[(r0) + 0][lane * 4]); \
    P##1 = *reinterpret_cast<const float4*>(&(buf)[(r0) + 1][lane * 4]); \
    P##2 = *reinterpret_cast<const float4*>(&(buf)[(r0) + 2][lane * 4]); \
    P##3 = *reinterpret_cast<const float4*>(&(buf)[(r0) + 3][lane * 4]); \
    P##4 = *reinterpret_cast<const float4*>(&(buf)[(r0) + 4][lane * 4]); \
    P##5 = *reinterpret_cast<const float4*>(&(buf)[(r0) + 5][lane * 4]); \
    P##6 = *reinterpret_cast<const float4*>(&(buf)[(r0) + 6][lane * 4]); \
    P##7 = *reinterpret_cast<const float4*>(&(buf)[(r0) + 7][lane * 4]);
#define ST8(P)                                                           \
    row_step(P##0); row_step(P##1); row_step(P##2); row_step(P##3);      \
    row_step(P##4); row_step(P##5); row_step(P##6); row_step(P##7);

        float4 A0, A1, A2, A3, A4, A5, A6, A7;
        float4 B0, B1, B2, B3, B4, B5, B6, B7;

        // chunk 0 (rows 0..15; peel row-0 init)
        {
            const float(*buf)[WW] = sbuf[imgi][0];
            RD8(A, buf, 0); RD8(B, buf, 8);
            v0 = A0.x; v1 = A0.y; v2 = A0.z; v3 = A0.w;
            row_step(A1); row_step(A2); row_step(A3);
            row_step(A4); row_step(A5); row_step(A6); row_step(A7);
            ST8(B);
        }
        // chunks 1..15
        for (int k = 1; k < NCH; ++k) {
            __syncthreads();                   // Bk
            const float(*buf)[WW] = sbuf[imgi][k & 1];
            RD8(A, buf, 0); RD8(B, buf, 8);
            ST8(A);
            ST8(B);
        }
#undef RD8
#undef ST8
        if (lane == 63) out[2 * blockIdx.x + imgi] = v3;
    } else {
        // ---------------- prep waves: 3 per image ----------------
        const int pw = (wid - 2) >> 1;         // 0,1,2
        {   // cooperative chunk-0: rows 4+4pw .. 7+4pw
            float4 C[4];
            load_rows<4>(gp, 4 + 4 * pw, C);
            prep_store<4>(C, &sbuf[imgi][0][4 + 4 * pw][0], lane);
        }
        const int row0 = (pw == 0) ? 0 : (pw == 1) ? 6 : 11;  // 6/5/5 rows
        float* b0 = &sbuf[imgi][0][row0][0];
        float* b1 = &sbuf[imgi][1][row0][0];
        if (pw == 0) prep_run<6>(gp, row0, b0, b1, lane);
        else         prep_run<5>(gp, row0, b0, b1, lane);
    }
}

extern "C" void kernel_launch(void* const* d_in, const int* in_sizes, int n_in,
                              void* d_out, int out_size, void* d_ws, size_t ws_size,
                              hipStream_t stream) {
    const float* img = (const float*)d_in[0];
    float* out = (float*)d_out;
    dp_kernel<<<out_size / 2, 512, 0, stream>>>(img, out);
}